// Round 1
// baseline (100.441 us; speedup 1.0000x reference)
//
#include <hip/hip_runtime.h>

// Problem constants (from reference)
#define NH 64
#define NW 64
#define ND 32
#define L  (NH * NW * ND)   // 131072
#define RH 3
#define RW 3
#define RD 1

__global__ __launch_bounds__(256)
void gatedcrf3d_kernel(const float* __restrict__ y,       // (2, L): y_hat_softmax
                       const float* __restrict__ sample,  // (1, L)
                       const float* __restrict__ spacing, // (3,)
                       float* __restrict__ out)           // (1,) pre-zeroed
{
    const int p = blockIdx.x * blockDim.x + threadIdx.x;

    float contrib = 0.0f;
    if (p < L) {
        // decompose p = h*2048 + w*32 + d
        const int d = p & (ND - 1);
        const int w = (p >> 5) & (NW - 1);
        const int h = p >> 11;

        const float inv_sxy = 1.0f / 5.0f;   // 1/SIGMA_XY
        const float inv_sim = 10.0f;         // 1/SIGMA_IMG

        const float sH = spacing[0] * inv_sxy;
        const float sW = spacing[1] * inv_sxy;
        const float sD = spacing[2] * inv_sxy;

        const float mh = sH * (float)h;
        const float mw = sW * (float)w;
        const float md = sD * (float)d;

        const float ic  = sample[p] * inv_sim;
        const float y0c = y[p];
        const float y1c = y[L + p];

        // out-of-bounds tap: features are 0 => diff = -center features
        const float k_oob = __expf(-0.5f * (mh*mh + mw*mw + md*md + ic*ic));

        float ksum = 0.0f, p0 = 0.0f, p1 = 0.0f;

        #pragma unroll
        for (int dh = -RH; dh <= RH; ++dh) {
            const int hh = h + dh;
            const float th = sH * (float)dh;
            const float th2 = th * th;
            #pragma unroll
            for (int dw = -RW; dw <= RW; ++dw) {
                const int ww = w + dw;
                const float tw = sW * (float)dw;
                const float thw2 = th2 + tw * tw;
                #pragma unroll
                for (int dd = -RD; dd <= RD; ++dd) {
                    if (dh == 0 && dw == 0 && dd == 0) continue; // center tap = 0
                    const int zz = d + dd;
                    const bool inb = ((unsigned)hh < NH) & ((unsigned)ww < NW) & ((unsigned)zz < ND);
                    if (inb) {
                        const int q = (hh << 11) + (ww << 5) + zz;
                        const float td = sD * (float)dd;
                        const float di = sample[q] * inv_sim - ic;
                        const float k = __expf(-0.5f * (thw2 + td * td + di * di));
                        ksum += k;
                        p0 += k * y[q];
                        p1 += k * y[L + q];
                    } else {
                        ksum += k_oob;
                    }
                }
            }
        }
        contrib = ksum - (p0 * y0c + p1 * y1c);
    }

    // wave64 reduction
    #pragma unroll
    for (int off = 32; off > 0; off >>= 1)
        contrib += __shfl_down(contrib, off, 64);

    __shared__ float red[4];
    const int lane = threadIdx.x & 63;
    const int wv   = threadIdx.x >> 6;
    if (lane == 0) red[wv] = contrib;
    __syncthreads();
    if (threadIdx.x == 0) {
        const float s = red[0] + red[1] + red[2] + red[3];
        atomicAdd(out, s * (1.0f / (float)L));
    }
}

extern "C" void kernel_launch(void* const* d_in, const int* in_sizes, int n_in,
                              void* d_out, int out_size, void* d_ws, size_t ws_size,
                              hipStream_t stream) {
    const float* y       = (const float*)d_in[0]; // y_hat_softmax (1,2,64,64,32)
    const float* sample  = (const float*)d_in[1]; // (1,1,64,64,32)
    const float* spacing = (const float*)d_in[2]; // (3,1)
    float* out = (float*)d_out;

    hipMemsetAsync(out, 0, sizeof(float), stream);

    const int threads = 256;
    const int blocks = (L + threads - 1) / threads; // 512
    gatedcrf3d_kernel<<<blocks, threads, 0, stream>>>(y, sample, spacing, out);
}

// Round 2
// 74.943 us; speedup vs baseline: 1.3402x; 1.3402x over previous
//
#include <hip/hip_runtime.h>

// Problem constants
#define NH 64
#define NW 64
#define ND 32
#define LTOT (NH * NW * ND)   // 131072

// Symmetric-pair formulation:
//   loss * L = sum_{unordered in-bounds pairs (p,q) in 7x7x3 nbhd} 2*k_pq*(1 - y0p*y0q - y1p*y1q)
//            + sum_p (147 - nh*nw*nd) * k_oob(p)
// where k_oob(p) = exp(-0.5*||center feats||^2)  (zero-padded unfold semantics).
// Half-offsets: (0,0,1) plus dd in {-1,0,1} for 24 (dh,dw) pairs:
// (0,1..3) and (1..3, -3..3). Two threads per voxel split the 24 pairs even/odd.

__global__ __launch_bounds__(256, 4)
void gatedcrf3d_kernel(const float* __restrict__ y,       // (2, L)
                       const float* __restrict__ sample,  // (1, L)
                       const float* __restrict__ spacing, // (3,)
                       float* __restrict__ out)           // (1,) pre-zeroed
{
    constexpr int cDH[24] = {0,0,0, 1,1,1,1,1,1,1, 2,2,2,2,2,2,2, 3,3,3,3,3,3,3};
    constexpr int cDW[24] = {1,2,3, -3,-2,-1,0,1,2,3, -3,-2,-1,0,1,2,3, -3,-2,-1,0,1,2,3};

    const int tid = threadIdx.x;
    const int sub = tid >> 7;                      // wave-uniform: waves 0,1 -> 0; waves 2,3 -> 1
    const int p   = blockIdx.x * 128 + (tid & 127);

    const int d = p & (ND - 1);
    const int w = (p >> 5) & (NW - 1);
    const int h = p >> 11;

    const float sH = spacing[0] * 0.2f;            // / SIGMA_XY
    const float sW = spacing[1] * 0.2f;
    const float sD = spacing[2] * 0.2f;
    const float nh2 = -0.5f * sH * sH;             // pre-scaled by -0.5 for exp arg
    const float nw2 = -0.5f * sW * sW;
    const float nd2 = -0.5f * sD * sD;

    const float ic  = sample[p] * 10.0f;           // / SIGMA_IMG
    const float y0c = y[p];
    const float y1c = y[LTOT + p];

    float acc   = 0.0f;   // sum of k*(1-dot) over this thread's half-taps (doubled later)
    float extra = 0.0f;   // OOB closed-form term (not doubled)

    auto pair_body = [&](int dh, int dw) {
        const int hh = h + dh;
        const int ww = w + dw;
        const bool ibhw = ((unsigned)hh < NH) & ((unsigned)ww < NW);
        const int hc = min(max(hh, 0), NH - 1);
        const int wc = min(max(ww, 0), NW - 1);
        const int qb = (hc << 11) + (wc << 5);
        const float spatHW = nh2 * (float)(dh * dh) + nw2 * (float)(dw * dw);
        #pragma unroll
        for (int dd = -1; dd <= 1; ++dd) {
            const int zz = d + dd;
            const bool inb = ibhw & ((unsigned)zz < ND);
            const int zc = min(max(zz, 0), ND - 1);
            const int q = qb + zc;
            const float sq  = sample[q];
            const float y0q = y[q];
            const float y1q = y[LTOT + q];
            const float di  = __builtin_fmaf(sq, 10.0f, -ic);
            const float spat = (dd == 0) ? spatHW : (spatHW + nd2);
            const float arg  = __builtin_fmaf(di, -0.5f * di, spat);
            const float k    = __expf(arg);
            const float t    = 1.0f - __builtin_fmaf(y0q, y0c, y1q * y1c);
            acc += inb ? (k * t) : 0.0f;
        }
    };

    if (sub == 0) {
        #pragma unroll
        for (int i = 0; i < 24; i += 2) pair_body(cDH[i], cDW[i]);
        // the lone (0,0,1) half-offset
        {
            const int zz = d + 1;
            const bool inb = zz < ND;
            const int q = (h << 11) + (w << 5) + (inb ? zz : d);
            const float di  = __builtin_fmaf(sample[q], 10.0f, -ic);
            const float arg = __builtin_fmaf(di, -0.5f * di, nd2);
            const float k   = __expf(arg);
            const float t   = 1.0f - __builtin_fmaf(y[q], y0c, y[LTOT + q] * y1c);
            acc += inb ? (k * t) : 0.0f;
        }
    } else {
        #pragma unroll
        for (int i = 1; i < 24; i += 2) pair_body(cDH[i], cDW[i]);
        // out-of-bounds taps: (147 - nh*nw*nd) * exp(-0.5*||center feats||^2)
        {
            const int nhv = min(h, 3) + min(NH - 1 - h, 3) + 1;
            const int nwv = min(w, 3) + min(NW - 1 - w, 3) + 1;
            const int ndv = min(d, 1) + min(ND - 1 - d, 1) + 1;
            const int cnt = 147 - nhv * nwv * ndv;
            const float argo = nh2 * (float)(h * h) + nw2 * (float)(w * w)
                             + nd2 * (float)(d * d) + (-0.5f) * ic * ic;
            extra = (float)cnt * __expf(argo);
        }
    }

    float contrib = __builtin_fmaf(2.0f, acc, extra);

    // wave64 reduction -> LDS -> one atomic per block
    #pragma unroll
    for (int off = 32; off > 0; off >>= 1)
        contrib += __shfl_down(contrib, off, 64);

    __shared__ float red[4];
    if ((tid & 63) == 0) red[tid >> 6] = contrib;
    __syncthreads();
    if (tid == 0) {
        atomicAdd(out, (red[0] + red[1] + red[2] + red[3]) * (1.0f / (float)LTOT));
    }
}

extern "C" void kernel_launch(void* const* d_in, const int* in_sizes, int n_in,
                              void* d_out, int out_size, void* d_ws, size_t ws_size,
                              hipStream_t stream) {
    const float* y       = (const float*)d_in[0]; // y_hat_softmax (1,2,64,64,32)
    const float* sample  = (const float*)d_in[1]; // (1,1,64,64,32)
    const float* spacing = (const float*)d_in[2]; // (3,1)
    float* out = (float*)d_out;

    hipMemsetAsync(out, 0, sizeof(float), stream);

    const int threads = 256;
    const int blocks = LTOT / 128;  // 1024 blocks, 2 threads per voxel
    gatedcrf3d_kernel<<<blocks, threads, 0, stream>>>(y, sample, spacing, out);
}